// Round 10
// baseline (144.131 us; speedup 1.0000x reference)
//
#include <hip/hip_runtime.h>
#include <math.h>

// SemanticDriftCoeff — band+prefix, v15: k_final fused into k_gemm3 via
// per-row-tile atomic counter (last block of tile-row ti computes out[] for
// its 64 rows; dmaxu re-read via atomicMax(p,0) = device-coherent read).
// prep2's pad-zeroing de-straggled (block 0's 7168 stores -> 256/block over
// blocks 0..27). 5 -> 4 launches. All output math identical to v14 (135.6).
// k_prep2 (256x16rows, fused zeroing), k_bandw (+segb wave 3), k_bandg
// (in-register prefix), k_gemm3 (v10 config) otherwise unchanged.
// ws: invnorm[T], dmaxu[T], gn2[T], dist2[T], invLb[T], Sseg[256*D],
// Eseg[256*D], cnt[64]; hb[T*D], hbTp[D*(T+64)], gb[T*D], wband[T*64] bf16.

#define T_ 4096
#define D_ 896
#define TP (T_ + 64)   // padded hbTp row stride (ushorts)
#define PSTR 900       // k_prep2 LDS row stride (ushorts), mult of 4, bank-spread

typedef float f32x4 __attribute__((ext_vector_type(4)));
typedef unsigned short u16x8 __attribute__((ext_vector_type(8)));
typedef __bf16 bf16x8 __attribute__((ext_vector_type(8)));

union V16 { uint4 u; u16x8 v; };

__device__ __forceinline__ u16x8 ld16(const unsigned short* p) {
  V16 x; x.u = *(const uint4*)p; return x.v;
}
__device__ __forceinline__ void st16(unsigned short* p, u16x8 v) {
  V16 x; x.v = v; *(uint4*)p = x.u;
}
__device__ __forceinline__ unsigned short f2bf(float f) {  // RNE float->bf16 bits
  unsigned int u = __float_as_uint(f);
  u += 0x7FFFu + ((u >> 16) & 1u);
  return (unsigned short)(u >> 16);
}
__device__ __forceinline__ float bf2f(unsigned short b) {
  return __uint_as_float(((unsigned int)b) << 16);
}
__device__ __forceinline__ f32x4 mfma16(u16x8 a, u16x8 b, f32x4 c) {
  return __builtin_amdgcn_mfma_f32_16x16x32_bf16(
      __builtin_bit_cast(bf16x8, a), __builtin_bit_cast(bf16x8, b), c, 0, 0, 0);
}

typedef __attribute__((address_space(1))) const void glob_cv;
typedef __attribute__((address_space(3))) void lds_v;
__device__ __forceinline__ void gload16(const void* g, void* l) {
  __builtin_amdgcn_global_load_lds((glob_cv*)g, (lds_v*)l, 16, 0, 0);
}

// 256-thread 64x64 bf16 tile stage with XOR group swizzle on the GLOBAL
// source (LDS dest linear, m173 pattern). 2 gload_lds per thread.
__device__ __forceinline__ void stage32(const unsigned short* __restrict__ g0,
                                        int stride, unsigned short* lds0, int tid) {
  #pragma unroll
  for (int it = 0; it < 2; ++it) {
    const int e = it * 256 + tid;            // e in [0,512)
    const int row = e >> 3, pg = e & 7;
    const int gg = pg ^ (row & 7);
    gload16(g0 + (size_t)row * stride + gg * 8, lds0 + e * 8);
  }
}

// Decode block id -> (ti: 64-row tile, sj: 128-col tile), causal.
// Row-pair p contributes 2(p+1) blocks; cumulative before p is p(p+1).
__device__ __forceinline__ void tri2_decode(int b, int& ti, int& sj) {
  int p = (int)((sqrtf(4.0f * (float)b + 1.0f) - 1.0f) * 0.5f);
  while ((p + 1) * (p + 2) <= b) ++p;
  while (p * (p + 1) > b) --p;
  const int r = b - p * (p + 1);
  if (r >= p + 1) { ti = 2 * p + 1; sj = r - (p + 1); }
  else            { ti = 2 * p;     sj = r; }
}

// ---------- prep2: invnorm + hb + hbTp + Sseg + ws zeroing (fused) ----------
__global__ __launch_bounds__(256, 2) void k_prep2(const float* __restrict__ x,
    float* __restrict__ invnorm, unsigned short* __restrict__ hb,
    unsigned short* __restrict__ hbTp, float* __restrict__ Sseg,
    float* __restrict__ zero3, unsigned int* __restrict__ cnt) {
  __shared__ unsigned short Ts[16 * PSTR];   // 28.8 KB
  const int b = (int)blockIdx.x;             // rows t0..t0+15 == segment b
  const int t0 = b * 16;
  const int tid = (int)threadIdx.x, wv = tid >> 6, lane = tid & 63;

  // zero dmaxu+gn2+dist2 (3T = 12288 words) from blocks 0..47; cnt from 48
  if (b < 48) zero3[b * 256 + tid] = 0.f;
  else if (b == 48 && tid < 64) cnt[tid] = 0u;

  // Each wave: 4 rows. Batch loads first (16 global loads in flight).
  float4 v[4][4];
  #pragma unroll
  for (int rr = 0; rr < 4; ++rr) {
    const int t = t0 + wv * 4 + rr;
    #pragma unroll
    for (int k = 0; k < 4; ++k) {
      const int c4 = lane + 64 * k;          // float4 index; 224 per row
      if (k < 3 || lane < 32)
        v[rr][k] = *(const float4*)(x + (size_t)t * D_ + c4 * 4);
    }
  }
  #pragma unroll
  for (int rr = 0; rr < 4; ++rr) {
    const int row = wv * 4 + rr;
    const int t = t0 + row;
    float s = 0.f;
    #pragma unroll
    for (int k = 0; k < 4; ++k)
      if (k < 3 || lane < 32)
        s += v[rr][k].x * v[rr][k].x + v[rr][k].y * v[rr][k].y +
             v[rr][k].z * v[rr][k].z + v[rr][k].w * v[rr][k].w;
    #pragma unroll
    for (int off = 32; off > 0; off >>= 1) s += __shfl_down(s, off, 64);
    const float iv = 1.0f / fmaxf(sqrtf(__shfl(s, 0, 64)), 1e-12f);
    if (lane == 0) invnorm[t] = iv;
    #pragma unroll
    for (int k = 0; k < 4; ++k) {
      const int c4 = lane + 64 * k;
      if (k < 3 || lane < 32) {
        const ushort4 o = make_ushort4(f2bf(v[rr][k].x * iv), f2bf(v[rr][k].y * iv),
                                       f2bf(v[rr][k].z * iv), f2bf(v[rr][k].w * iv));
        *(ushort4*)(hb + (size_t)t * D_ + c4 * 4) = o;
        *(ushort4*)(&Ts[row * PSTR + c4 * 4]) = o;
      }
    }
  }
  __syncthreads();

  // Sseg[b][c]: sum of the 16 rows in 4-row groups, left-assoc (sega order).
  for (int c = tid; c < D_; c += 256) {
    float segsum = 0.f;
    #pragma unroll
    for (int q = 0; q < 4; ++q) {
      float gs = 0.f;
      #pragma unroll
      for (int r = 0; r < 4; ++r)
        gs += bf2f(Ts[(q * 4 + r) * PSTR + c]);
      segsum += gs;
    }
    Sseg[(size_t)b * D_ + c] = segsum;
  }

  // Transpose: hbTp[d][32 + t0 + 0..15] for all 896 d. 3584 ushort4 stores.
  #pragma unroll 2
  for (int it = 0; it < 14; ++it) {
    const int e = it * 256 + tid;            // 0..3583
    const int d = e >> 2, q = e & 3;
    const ushort4 o = make_ushort4(Ts[(q * 4 + 0) * PSTR + d],
                                   Ts[(q * 4 + 1) * PSTR + d],
                                   Ts[(q * 4 + 2) * PSTR + d],
                                   Ts[(q * 4 + 3) * PSTR + d]);
    *(ushort4*)(hbTp + (size_t)d * TP + 32 + t0 + q * 4) = o;
  }
  // zero the 32 leading pad cols, 32 d-rows per block (blocks 0..27)
  if (b < 28) {
    const int d = b * 32 + (tid >> 3), cc = (tid & 7) * 4;
    *(ushort4*)(hbTp + (size_t)d * TP + cc) = make_ushort4(0, 0, 0, 0);
  }
}

// ---------- bandw (+segb in wave 3): sims -> weights + invL; column scan ----------
__global__ __launch_bounds__(256) void k_bandw(const unsigned short* __restrict__ hb,
    const float* __restrict__ Sseg, float* __restrict__ Eseg,
    unsigned short* __restrict__ wband, float* __restrict__ invLb) {
  const int b = (int)blockIdx.x;
  const int t0 = b * 16;
  const int tid = (int)threadIdx.x;
  const int wv = tid >> 6, lane = tid & 63;
  const int tcol = lane & 15, quad = lane >> 4;
  __shared__ float sims[16][52];
  if (wv < 3) {
    const int s_base = t0 - 32 + wv * 16;
    if (s_base + 15 >= 0) {
      const int srow = max(s_base + tcol, 0);   // clamped; guarded below
      f32x4 acc = {};
      const unsigned short* arow = hb + (size_t)srow * D_ + quad * 8;
      const unsigned short* brow = hb + (size_t)(t0 + tcol) * D_ + quad * 8;
      #pragma unroll 1
      for (int c4 = 0; c4 < 4; ++c4) {          // 7 load-pairs in flight per step
        u16x8 av[7], bv[7];
        #pragma unroll
        for (int i = 0; i < 7; ++i) {
          av[i] = ld16(arow + (c4 * 7 + i) * 32);
          bv[i] = ld16(brow + (c4 * 7 + i) * 32);
        }
        #pragma unroll
        for (int i = 0; i < 7; ++i) acc = mfma16(av[i], bv[i], acc);
      }
      #pragma unroll
      for (int r = 0; r < 4; ++r)       // C[m=s_local=quad*4+r][n=t_local=tcol]
        sims[tcol][wv * 16 + quad * 4 + r] = acc[r];
    }
  } else if (b < 224) {
    // wave 3 (idle in phase 1): the former k_segb, 4 columns sequentially.
    #pragma unroll 1
    for (int cc = 0; cc < 4; ++cc) {
      const int c = b * 4 + cc;                 // column 0..895
      float v0 = Sseg[(size_t)lane * D_ + c];
      float v1 = Sseg[(size_t)(64 + lane) * D_ + c];
      float v2 = Sseg[(size_t)(128 + lane) * D_ + c];
      float v3 = Sseg[(size_t)(192 + lane) * D_ + c];
      const float o0 = v0, o1 = v1, o2 = v2, o3 = v3;
      #pragma unroll
      for (int off = 1; off < 64; off <<= 1) {
        const float n0 = __shfl_up(v0, off, 64);
        const float n1 = __shfl_up(v1, off, 64);
        const float n2 = __shfl_up(v2, off, 64);
        const float n3 = __shfl_up(v3, off, 64);
        if (lane >= off) { v0 += n0; v1 += n1; v2 += n2; v3 += n3; }
      }
      const float tot0 = __shfl(v0, 63, 64);
      const float tot1 = __shfl(v1, 63, 64);
      const float tot2 = __shfl(v2, 63, 64);
      Eseg[(size_t)lane * D_ + c] = v0 - o0;              // exclusive
      Eseg[(size_t)(64 + lane) * D_ + c] = v1 - o1 + tot0;
      Eseg[(size_t)(128 + lane) * D_ + c] = v2 - o2 + (tot0 + tot1);
      Eseg[(size_t)(192 + lane) * D_ + c] = v3 - o3 + (tot0 + tot1 + tot2);
    }
  }
  __syncthreads();
  if (wv == 0) {
    u16x8 af0, af1;
    float lsum = 0.f;
    #pragma unroll
    for (int j = 0; j < 8; ++j) {
      {
        const int k = quad * 8 + j;                 // k in [0,32)
        const int dt = tcol + 32 - k;               // >= 1
        const int s = t0 - 32 + k;
        unsigned short wb = 0;
        if (dt < 32 && s >= 0)
          wb = f2bf(__expf(sims[tcol][k] * (__expf(-0.1f * (float)dt) * 0.033407657f)));
        af0[j] = wb;
        lsum += bf2f(wb);
      }
      {
        const int k = 32 + quad * 8 + j;            // k in [32,64)
        const int dt = tcol + 32 - k;               // <= 15
        unsigned short wb = 0;
        if (dt >= 0)                                // k <= tcol+32 <= 47
          wb = f2bf(__expf(sims[tcol][k] * (__expf(-0.1f * (float)dt) * 0.033407657f)));
        af1[j] = wb;
        lsum += bf2f(wb);
      }
    }
    lsum += __shfl_xor(lsum, 16, 64);
    lsum += __shfl_xor(lsum, 32, 64);
    st16(wband + (size_t)(t0 + tcol) * 64 + quad * 8, af0);
    st16(wband + (size_t)(t0 + tcol) * 64 + 32 + quad * 8, af1);
    if (lane < 16) {
      const int t = t0 + lane;
      invLb[t] = 1.0f / (lsum + ((t >= 32) ? (float)(t - 31) : 0.f));
    }
  }
}

// ---------- bandg: band GEMM + in-register prefix (P eliminated) ----------
__global__ __launch_bounds__(256) void k_bandg(const unsigned short* __restrict__ hbTp,
    const unsigned short* __restrict__ wband, const float* __restrict__ invLb,
    const float* __restrict__ Eseg, const float* __restrict__ x,
    const float* __restrict__ invnorm, unsigned short* __restrict__ gb,
    float* __restrict__ gn2, float* __restrict__ dist2) {
  const int t0 = (int)blockIdx.x * 16;
  const int by = (int)blockIdx.y;             // 8 d-groups of 7 tiles
  const int tid = (int)threadIdx.x;
  const int wv = tid >> 6, lane = tid & 63;
  const int tcol = lane & 15, quad = lane >> 4;
  const u16x8 af0 = ld16(wband + (size_t)(t0 + tcol) * 64 + quad * 8);
  const u16x8 af1 = ld16(wband + (size_t)(t0 + tcol) * 64 + 32 + quad * 8);
  const int sg = (t0 >> 4) - 2;               // segment of rows t0-32..t0-17
  float invLr[4], inrr[4];
  #pragma unroll
  for (int r = 0; r < 4; ++r) {
    const int tt = t0 + quad * 4 + r;
    invLr[r] = invLb[tt];
    inrr[r]  = invnorm[tt];
  }
  float sgl[4] = {0.f, 0.f, 0.f, 0.f}, sdl[4] = {0.f, 0.f, 0.f, 0.f};
  for (int i = wv; i < 7; i += 4) {
    const int d = (by * 7 + i) * 16 + tcol;
    const unsigned short* brow = hbTp + (size_t)d * TP + t0 + quad * 8;
    const u16x8 b0 = ld16(brow);          // k in [0,32): zeros where s<0
    const u16x8 b1 = ld16(brow + 32);     // k in [32,64): tail x w=0 harmless
    f32x4 C = {};
    C = mfma16(af0, b0, C);
    C = mfma16(af1, b1, C);
    // P(t0-32+j) recomputed in-register: Eseg[sg][d] + sequential bf16 adds
    // over hbTp[d][t0 .. t0+15] (rows t0-32..t0-17). Same f32 order as the
    // old k_segc -> bit-identical.
    float pr[4] = {0.f, 0.f, 0.f, 0.f};
    if (t0 >= 32) {
      const unsigned short* prow = hbTp + (size_t)d * TP + t0;
      const uint4 w0 = *(const uint4*)prow;
      const uint4 w1 = *(const uint4*)(prow + 8);
      const unsigned int wz[8] = {w0.x, w0.y, w0.z, w0.w, w1.x, w1.y, w1.z, w1.w};
      float run = Eseg[(size_t)sg * D_ + d];
      #pragma unroll
      for (int jj = 0; jj < 16; ++jj) {
        const unsigned int uu = wz[jj >> 1];
        const unsigned short hh =
            (jj & 1) ? (unsigned short)(uu >> 16) : (unsigned short)(uu & 0xffffu);
        run += bf2f(hh);
        if ((jj >> 2) == quad) pr[jj & 3] = run;
      }
    }
    #pragma unroll
    for (int r = 0; r < 4; ++r) {     // C[m=quad*4+r -> t][n=tcol -> d]
      const int tt = t0 + quad * 4 + r;
      float gacc = C[r];
      if (tt >= 32) gacc += pr[r];
      const float g = gacc * invLr[r];
      gb[(size_t)tt * D_ + d] = f2bf(g);
      const float e = x[(size_t)tt * D_ + d] * inrr[r] - g;
      sgl[r] += g * g;
      sdl[r] += e * e;
    }
  }
  #pragma unroll
  for (int r = 0; r < 4; ++r) {
    float sg2 = sgl[r], sd = sdl[r];
    sg2 += __shfl_xor(sg2, 1, 64); sg2 += __shfl_xor(sg2, 2, 64);
    sg2 += __shfl_xor(sg2, 4, 64); sg2 += __shfl_xor(sg2, 8, 64);
    sd += __shfl_xor(sd, 1, 64); sd += __shfl_xor(sd, 2, 64);
    sd += __shfl_xor(sd, 4, 64); sd += __shfl_xor(sd, 8, 64);
    if (tcol == 0) {
      atomicAdd(&gn2[t0 + quad * 4 + r], sg2);
      atomicAdd(&dist2[t0 + quad * 4 + r], sd);
    }
  }
}

// ---------- GEMM3 (+final): cross = g h^T, 64x128 causal tiles; row-max ----------
// v10 config (best measured) + fused finalization: last block of tile-row ti
// (cnt[ti] == ti/2+1 - 1) computes out[] for its 64 rows. dmaxu re-read with
// atomicMax(p,0) (device-coherent); dist2/m_t/c_t/d_t/mu are pre-launch data.
__global__ __launch_bounds__(256, 5) void k_gemm3(const unsigned short* __restrict__ gb,
    const unsigned short* __restrict__ hb, const float* __restrict__ gn2,
    unsigned int* __restrict__ dmaxu, unsigned int* __restrict__ cnt,
    const float* __restrict__ dist2, const float* __restrict__ m_t,
    const float* __restrict__ c_t, const float* __restrict__ d_t,
    const float* __restrict__ mu, float* __restrict__ out) {
  // Bijective XCD swizzle: 1056 = 8*132.
  const int bswz = ((int)blockIdx.x & 7) * 132 + ((int)blockIdx.x >> 3);
  int ti, sj;
  tri2_decode(bswz, ti, sj);
  const int t0 = ti * 64, s0 = sj * 128;
  __shared__ unsigned short As[64 * 64];    // 8 KB  (t rows)
  __shared__ unsigned short Bs[128 * 64];   // 16 KB (s rows)
  __shared__ unsigned int dmx[64];          // per-block row-max merge
  __shared__ int lastflag;
  const int tid = (int)threadIdx.x;
  const int lane = tid & 63, wv = tid >> 6;
  const int tcol = lane & 15, quad = lane >> 4;
  if (tid < 64) dmx[tid] = 0u;
  f32x4 acc[4][2] = {};

  for (int kc = 0; kc < 14; ++kc) {
    __syncthreads();   // prev chunk's reads done before overwrite (also fences dmx init)
    stage32(gb + (size_t)t0 * D_ + kc * 64, D_, As, tid);
    stage32(hb + (size_t)s0 * D_ + kc * 64, D_, Bs, tid);
    stage32(hb + (size_t)(s0 + 64) * D_ + kc * 64, D_, Bs + 64 * 64, tid);
    __syncthreads();   // staged data visible
    #pragma unroll
    for (int ks = 0; ks < 2; ++ks) {
      const int go = ((ks * 4 + quad) ^ (tcol & 7)) * 8;
      u16x8 bf[2], af[4];
      #pragma unroll
      for (int ni = 0; ni < 2; ++ni)
        bf[ni] = ld16(&Bs[(wv * 32 + ni * 16 + tcol) * 64 + go]);
      #pragma unroll
      for (int mi = 0; mi < 4; ++mi)
        af[mi] = ld16(&As[(mi * 16 + tcol) * 64 + go]);
      #pragma unroll
      for (int mi = 0; mi < 4; ++mi)
        #pragma unroll
        for (int ni = 0; ni < 2; ++ni)
          acc[mi][ni] = mfma16(af[mi], bf[ni], acc[mi][ni]);
    }
  }

  // epilogue: m2[t] = max over this wave's 32-col strip, merge in LDS, then global
  #pragma unroll
  for (int mi = 0; mi < 4; ++mi) {
    #pragma unroll
    for (int r = 0; r < 4; ++r) {
      const int t = t0 + mi * 16 + quad * 4 + r;
      const float gn = gn2[t];
      float m2 = 0.f;
      #pragma unroll
      for (int ni = 0; ni < 2; ++ni) {
        const int s = s0 + wv * 32 + ni * 16 + tcol;
        if (t >= s)
          m2 = fmaxf(m2, fmaxf(1.0f - 2.0f * acc[mi][ni][r] + gn, 1e-24f));
      }
      m2 = fmaxf(m2, __shfl_xor(m2, 1, 64));
      m2 = fmaxf(m2, __shfl_xor(m2, 2, 64));
      m2 = fmaxf(m2, __shfl_xor(m2, 4, 64));
      m2 = fmaxf(m2, __shfl_xor(m2, 8, 64));
      if (tcol == 0 && m2 > 0.f)
        atomicMax(&dmx[mi * 16 + quad * 4 + r], __float_as_uint(m2));
    }
  }
  __syncthreads();
  if (tid < 64) {
    const unsigned int v = dmx[tid];
    if (v) atomicMax(&dmaxu[t0 + tid], v);
    __threadfence();   // make this block's dmaxu updates device-visible
  }
  __syncthreads();
  if (tid == 0) {
    const unsigned int need = (unsigned int)(ti / 2 + 1);
    const unsigned int pos = atomicAdd(&cnt[ti], 1u);
    lastflag = (pos == need - 1u) ? 1 : 0;
  }
  __syncthreads();
  if (lastflag && tid < 64) {
    const int t = t0 + tid;
    float ratio;
    if (t == 0) {
      ratio = 0.f;  // ref: dist~1e-12, dist_max<1e-6 -> 1.0 => ratio ~0
    } else {
      // atomic read: device-coherent view of concurrent atomicMax updates
      const unsigned int du = atomicMax(&dmaxu[t], 0u);
      float dmax = sqrtf(__uint_as_float(du));
      if (dmax < 1e-6f) dmax = 1.0f;
      ratio = sqrtf(fmaxf(dist2[t], 1e-24f)) / (dmax + 1e-8f);
    }
    const float stab = 1.0f - 0.3f * c_t[t] + 0.2f * d_t[t];
    const float xi = 1.0f - mu[0] * m_t[t];
    out[t] = fminf(fmaxf(ratio * stab * xi, 0.f), 1.f);
  }
}

extern "C" void kernel_launch(void* const* d_in, const int* in_sizes, int n_in,
                              void* d_out, int out_size, void* d_ws, size_t ws_size,
                              hipStream_t stream) {
  const float* x   = (const float*)d_in[0];
  const float* m_t = (const float*)d_in[1];
  const float* c_t = (const float*)d_in[2];
  const float* d_t = (const float*)d_in[3];
  const float* mu  = (const float*)d_in[4];
  float* out = (float*)d_out;

  float* ws = (float*)d_ws;
  float* invnorm = ws;                                          // [T]
  unsigned int* dmaxu = (unsigned int*)(ws + (size_t)T_);       // [T]
  float* gn2     = ws + 2 * (size_t)T_;                         // [T]
  float* dist2   = ws + 3 * (size_t)T_;                         // [T]
  float* invLb   = ws + 4 * (size_t)T_;                         // [T]
  float* Sseg    = ws + 5 * (size_t)T_;                         // [256*D]
  float* Eseg    = Sseg + 256 * (size_t)D_;                     // [256*D]
  unsigned int* cnt = (unsigned int*)(Eseg + 256 * (size_t)D_); // [64]
  float* Pold    = Eseg + 256 * (size_t)D_ + 256;               // (unused region)
  unsigned short* hb    = (unsigned short*)(Pold + (size_t)T_ * D_);  // [T*D]
  unsigned short* hbTp  = hb + (size_t)T_ * D_;                    // [D*(T+64)]
  unsigned short* gb    = hbTp + (size_t)D_ * TP;                  // [T*D]
  unsigned short* wband = gb + (size_t)T_ * D_;                    // [T*64]

  float* zero3 = ws + (size_t)T_;   // dmaxu+gn2+dist2, zeroed inside k_prep2

  k_prep2<<<T_ / 16, 256, 0, stream>>>(x, invnorm, hb, hbTp, Sseg, zero3, cnt);
  k_bandw<<<T_ / 16, 256, 0, stream>>>(hb, Sseg, Eseg, wband, invLb);
  k_bandg<<<dim3(T_ / 16, 8), 256, 0, stream>>>(hbTp, wband, invLb, Eseg, x, invnorm,
                                                gb, gn2, dist2);
  k_gemm3<<<1056, 256, 0, stream>>>(gb, hb, gn2, dmaxu, cnt, dist2,
                                    m_t, c_t, d_t, mu, out);
}

// Round 11
// 132.073 us; speedup vs baseline: 1.0913x; 1.0913x over previous
//
#include <hip/hip_runtime.h>
#include <math.h>

// SemanticDriftCoeff — band+prefix, v16: revert v15's k_final fusion
// (its per-block __threadfence = cross-XCD L2 writeback x1056 cost ~13us
// on k_gemm3: 30 -> 43.7us measured in R10). Back to v14 structure
// (best: 135.6us), keeping v15's one good piece: prep2 pad-zeroing
// de-straggled (block 0's 7168 serial stores -> 256/block, blocks 0..27).
// 5 launches: prep2, bandw(+segb), bandg, gemm3, final.
// ws: invnorm[T], dmaxu[T], gn2[T], dist2[T], invLb[T], Sseg[256*D],
// Eseg[256*D]; hb[T*D], hbTp[D*(T+64)], gb[T*D], wband[T*64] bf16.

#define T_ 4096
#define D_ 896
#define TP (T_ + 64)   // padded hbTp row stride (ushorts)
#define PSTR 900       // k_prep2 LDS row stride (ushorts), mult of 4, bank-spread

typedef float f32x4 __attribute__((ext_vector_type(4)));
typedef unsigned short u16x8 __attribute__((ext_vector_type(8)));
typedef __bf16 bf16x8 __attribute__((ext_vector_type(8)));

union V16 { uint4 u; u16x8 v; };

__device__ __forceinline__ u16x8 ld16(const unsigned short* p) {
  V16 x; x.u = *(const uint4*)p; return x.v;
}
__device__ __forceinline__ void st16(unsigned short* p, u16x8 v) {
  V16 x; x.v = v; *(uint4*)p = x.u;
}
__device__ __forceinline__ unsigned short f2bf(float f) {  // RNE float->bf16 bits
  unsigned int u = __float_as_uint(f);
  u += 0x7FFFu + ((u >> 16) & 1u);
  return (unsigned short)(u >> 16);
}
__device__ __forceinline__ float bf2f(unsigned short b) {
  return __uint_as_float(((unsigned int)b) << 16);
}
__device__ __forceinline__ f32x4 mfma16(u16x8 a, u16x8 b, f32x4 c) {
  return __builtin_amdgcn_mfma_f32_16x16x32_bf16(
      __builtin_bit_cast(bf16x8, a), __builtin_bit_cast(bf16x8, b), c, 0, 0, 0);
}

typedef __attribute__((address_space(1))) const void glob_cv;
typedef __attribute__((address_space(3))) void lds_v;
__device__ __forceinline__ void gload16(const void* g, void* l) {
  __builtin_amdgcn_global_load_lds((glob_cv*)g, (lds_v*)l, 16, 0, 0);
}

// 256-thread 64x64 bf16 tile stage with XOR group swizzle on the GLOBAL
// source (LDS dest linear, m173 pattern). 2 gload_lds per thread.
__device__ __forceinline__ void stage32(const unsigned short* __restrict__ g0,
                                        int stride, unsigned short* lds0, int tid) {
  #pragma unroll
  for (int it = 0; it < 2; ++it) {
    const int e = it * 256 + tid;            // e in [0,512)
    const int row = e >> 3, pg = e & 7;
    const int gg = pg ^ (row & 7);
    gload16(g0 + (size_t)row * stride + gg * 8, lds0 + e * 8);
  }
}

// Decode block id -> (ti: 64-row tile, sj: 128-col tile), causal.
// Row-pair p contributes 2(p+1) blocks; cumulative before p is p(p+1).
__device__ __forceinline__ void tri2_decode(int b, int& ti, int& sj) {
  int p = (int)((sqrtf(4.0f * (float)b + 1.0f) - 1.0f) * 0.5f);
  while ((p + 1) * (p + 2) <= b) ++p;
  while (p * (p + 1) > b) --p;
  const int r = b - p * (p + 1);
  if (r >= p + 1) { ti = 2 * p + 1; sj = r - (p + 1); }
  else            { ti = 2 * p;     sj = r; }
}

// ---------- prep2: invnorm + hb + hbTp + Sseg + ws zeroing (fused) ----------
__global__ __launch_bounds__(256, 2) void k_prep2(const float* __restrict__ x,
    float* __restrict__ invnorm, unsigned short* __restrict__ hb,
    unsigned short* __restrict__ hbTp, float* __restrict__ Sseg,
    float* __restrict__ zero3) {
  __shared__ unsigned short Ts[16 * PSTR];   // 28.8 KB
  const int b = (int)blockIdx.x;             // rows t0..t0+15 == segment b
  const int t0 = b * 16;
  const int tid = (int)threadIdx.x, wv = tid >> 6, lane = tid & 63;

  // zero dmaxu+gn2+dist2 (3T = 12288 words) from blocks 0..47
  if (b < 48) zero3[b * 256 + tid] = 0.f;

  // Each wave: 4 rows. Batch loads first (16 global loads in flight).
  float4 v[4][4];
  #pragma unroll
  for (int rr = 0; rr < 4; ++rr) {
    const int t = t0 + wv * 4 + rr;
    #pragma unroll
    for (int k = 0; k < 4; ++k) {
      const int c4 = lane + 64 * k;          // float4 index; 224 per row
      if (k < 3 || lane < 32)
        v[rr][k] = *(const float4*)(x + (size_t)t * D_ + c4 * 4);
    }
  }
  #pragma unroll
  for (int rr = 0; rr < 4; ++rr) {
    const int row = wv * 4 + rr;
    const int t = t0 + row;
    float s = 0.f;
    #pragma unroll
    for (int k = 0; k < 4; ++k)
      if (k < 3 || lane < 32)
        s += v[rr][k].x * v[rr][k].x + v[rr][k].y * v[rr][k].y +
             v[rr][k].z * v[rr][k].z + v[rr][k].w * v[rr][k].w;
    #pragma unroll
    for (int off = 32; off > 0; off >>= 1) s += __shfl_down(s, off, 64);
    const float iv = 1.0f / fmaxf(sqrtf(__shfl(s, 0, 64)), 1e-12f);
    if (lane == 0) invnorm[t] = iv;
    #pragma unroll
    for (int k = 0; k < 4; ++k) {
      const int c4 = lane + 64 * k;
      if (k < 3 || lane < 32) {
        const ushort4 o = make_ushort4(f2bf(v[rr][k].x * iv), f2bf(v[rr][k].y * iv),
                                       f2bf(v[rr][k].z * iv), f2bf(v[rr][k].w * iv));
        *(ushort4*)(hb + (size_t)t * D_ + c4 * 4) = o;
        *(ushort4*)(&Ts[row * PSTR + c4 * 4]) = o;
      }
    }
  }
  __syncthreads();

  // Sseg[b][c]: sum of the 16 rows in 4-row groups, left-assoc (sega order).
  for (int c = tid; c < D_; c += 256) {
    float segsum = 0.f;
    #pragma unroll
    for (int q = 0; q < 4; ++q) {
      float gs = 0.f;
      #pragma unroll
      for (int r = 0; r < 4; ++r)
        gs += bf2f(Ts[(q * 4 + r) * PSTR + c]);
      segsum += gs;
    }
    Sseg[(size_t)b * D_ + c] = segsum;
  }

  // Transpose: hbTp[d][32 + t0 + 0..15] for all 896 d. 3584 ushort4 stores.
  #pragma unroll 2
  for (int it = 0; it < 14; ++it) {
    const int e = it * 256 + tid;            // 0..3583
    const int d = e >> 2, q = e & 3;
    const ushort4 o = make_ushort4(Ts[(q * 4 + 0) * PSTR + d],
                                   Ts[(q * 4 + 1) * PSTR + d],
                                   Ts[(q * 4 + 2) * PSTR + d],
                                   Ts[(q * 4 + 3) * PSTR + d]);
    *(ushort4*)(hbTp + (size_t)d * TP + 32 + t0 + q * 4) = o;
  }
  // zero the 32 leading pad cols, 32 d-rows per block (blocks 0..27)
  if (b < 28) {
    const int d = b * 32 + (tid >> 3), cc = (tid & 7) * 4;
    *(ushort4*)(hbTp + (size_t)d * TP + cc) = make_ushort4(0, 0, 0, 0);
  }
}

// ---------- bandw (+segb in wave 3): sims -> weights + invL; column scan ----------
__global__ __launch_bounds__(256) void k_bandw(const unsigned short* __restrict__ hb,
    const float* __restrict__ Sseg, float* __restrict__ Eseg,
    unsigned short* __restrict__ wband, float* __restrict__ invLb) {
  const int b = (int)blockIdx.x;
  const int t0 = b * 16;
  const int tid = (int)threadIdx.x;
  const int wv = tid >> 6, lane = tid & 63;
  const int tcol = lane & 15, quad = lane >> 4;
  __shared__ float sims[16][52];
  if (wv < 3) {
    const int s_base = t0 - 32 + wv * 16;
    if (s_base + 15 >= 0) {
      const int srow = max(s_base + tcol, 0);   // clamped; guarded below
      f32x4 acc = {};
      const unsigned short* arow = hb + (size_t)srow * D_ + quad * 8;
      const unsigned short* brow = hb + (size_t)(t0 + tcol) * D_ + quad * 8;
      #pragma unroll 1
      for (int c4 = 0; c4 < 4; ++c4) {          // 7 load-pairs in flight per step
        u16x8 av[7], bv[7];
        #pragma unroll
        for (int i = 0; i < 7; ++i) {
          av[i] = ld16(arow + (c4 * 7 + i) * 32);
          bv[i] = ld16(brow + (c4 * 7 + i) * 32);
        }
        #pragma unroll
        for (int i = 0; i < 7; ++i) acc = mfma16(av[i], bv[i], acc);
      }
      #pragma unroll
      for (int r = 0; r < 4; ++r)       // C[m=s_local=quad*4+r][n=t_local=tcol]
        sims[tcol][wv * 16 + quad * 4 + r] = acc[r];
    }
  } else if (b < 224) {
    // wave 3 (idle in phase 1): the former k_segb, 4 columns sequentially.
    #pragma unroll 1
    for (int cc = 0; cc < 4; ++cc) {
      const int c = b * 4 + cc;                 // column 0..895
      float v0 = Sseg[(size_t)lane * D_ + c];
      float v1 = Sseg[(size_t)(64 + lane) * D_ + c];
      float v2 = Sseg[(size_t)(128 + lane) * D_ + c];
      float v3 = Sseg[(size_t)(192 + lane) * D_ + c];
      const float o0 = v0, o1 = v1, o2 = v2, o3 = v3;
      #pragma unroll
      for (int off = 1; off < 64; off <<= 1) {
        const float n0 = __shfl_up(v0, off, 64);
        const float n1 = __shfl_up(v1, off, 64);
        const float n2 = __shfl_up(v2, off, 64);
        const float n3 = __shfl_up(v3, off, 64);
        if (lane >= off) { v0 += n0; v1 += n1; v2 += n2; v3 += n3; }
      }
      const float tot0 = __shfl(v0, 63, 64);
      const float tot1 = __shfl(v1, 63, 64);
      const float tot2 = __shfl(v2, 63, 64);
      Eseg[(size_t)lane * D_ + c] = v0 - o0;              // exclusive
      Eseg[(size_t)(64 + lane) * D_ + c] = v1 - o1 + tot0;
      Eseg[(size_t)(128 + lane) * D_ + c] = v2 - o2 + (tot0 + tot1);
      Eseg[(size_t)(192 + lane) * D_ + c] = v3 - o3 + (tot0 + tot1 + tot2);
    }
  }
  __syncthreads();
  if (wv == 0) {
    u16x8 af0, af1;
    float lsum = 0.f;
    #pragma unroll
    for (int j = 0; j < 8; ++j) {
      {
        const int k = quad * 8 + j;                 // k in [0,32)
        const int dt = tcol + 32 - k;               // >= 1
        const int s = t0 - 32 + k;
        unsigned short wb = 0;
        if (dt < 32 && s >= 0)
          wb = f2bf(__expf(sims[tcol][k] * (__expf(-0.1f * (float)dt) * 0.033407657f)));
        af0[j] = wb;
        lsum += bf2f(wb);
      }
      {
        const int k = 32 + quad * 8 + j;            // k in [32,64)
        const int dt = tcol + 32 - k;               // <= 15
        unsigned short wb = 0;
        if (dt >= 0)                                // k <= tcol+32 <= 47
          wb = f2bf(__expf(sims[tcol][k] * (__expf(-0.1f * (float)dt) * 0.033407657f)));
        af1[j] = wb;
        lsum += bf2f(wb);
      }
    }
    lsum += __shfl_xor(lsum, 16, 64);
    lsum += __shfl_xor(lsum, 32, 64);
    st16(wband + (size_t)(t0 + tcol) * 64 + quad * 8, af0);
    st16(wband + (size_t)(t0 + tcol) * 64 + 32 + quad * 8, af1);
    if (lane < 16) {
      const int t = t0 + lane;
      invLb[t] = 1.0f / (lsum + ((t >= 32) ? (float)(t - 31) : 0.f));
    }
  }
}

// ---------- bandg: band GEMM + in-register prefix (P eliminated) ----------
__global__ __launch_bounds__(256) void k_bandg(const unsigned short* __restrict__ hbTp,
    const unsigned short* __restrict__ wband, const float* __restrict__ invLb,
    const float* __restrict__ Eseg, const float* __restrict__ x,
    const float* __restrict__ invnorm, unsigned short* __restrict__ gb,
    float* __restrict__ gn2, float* __restrict__ dist2) {
  const int t0 = (int)blockIdx.x * 16;
  const int by = (int)blockIdx.y;             // 8 d-groups of 7 tiles
  const int tid = (int)threadIdx.x;
  const int wv = tid >> 6, lane = tid & 63;
  const int tcol = lane & 15, quad = lane >> 4;
  const u16x8 af0 = ld16(wband + (size_t)(t0 + tcol) * 64 + quad * 8);
  const u16x8 af1 = ld16(wband + (size_t)(t0 + tcol) * 64 + 32 + quad * 8);
  const int sg = (t0 >> 4) - 2;               // segment of rows t0-32..t0-17
  float invLr[4], inrr[4];
  #pragma unroll
  for (int r = 0; r < 4; ++r) {
    const int tt = t0 + quad * 4 + r;
    invLr[r] = invLb[tt];
    inrr[r]  = invnorm[tt];
  }
  float sgl[4] = {0.f, 0.f, 0.f, 0.f}, sdl[4] = {0.f, 0.f, 0.f, 0.f};
  for (int i = wv; i < 7; i += 4) {
    const int d = (by * 7 + i) * 16 + tcol;
    const unsigned short* brow = hbTp + (size_t)d * TP + t0 + quad * 8;
    const u16x8 b0 = ld16(brow);          // k in [0,32): zeros where s<0
    const u16x8 b1 = ld16(brow + 32);     // k in [32,64): tail x w=0 harmless
    f32x4 C = {};
    C = mfma16(af0, b0, C);
    C = mfma16(af1, b1, C);
    // P(t0-32+j) recomputed in-register: Eseg[sg][d] + sequential bf16 adds
    // over hbTp[d][t0 .. t0+15] (rows t0-32..t0-17). Same f32 order as the
    // old k_segc -> bit-identical.
    float pr[4] = {0.f, 0.f, 0.f, 0.f};
    if (t0 >= 32) {
      const unsigned short* prow = hbTp + (size_t)d * TP + t0;
      const uint4 w0 = *(const uint4*)prow;
      const uint4 w1 = *(const uint4*)(prow + 8);
      const unsigned int wz[8] = {w0.x, w0.y, w0.z, w0.w, w1.x, w1.y, w1.z, w1.w};
      float run = Eseg[(size_t)sg * D_ + d];
      #pragma unroll
      for (int jj = 0; jj < 16; ++jj) {
        const unsigned int uu = wz[jj >> 1];
        const unsigned short hh =
            (jj & 1) ? (unsigned short)(uu >> 16) : (unsigned short)(uu & 0xffffu);
        run += bf2f(hh);
        if ((jj >> 2) == quad) pr[jj & 3] = run;
      }
    }
    #pragma unroll
    for (int r = 0; r < 4; ++r) {     // C[m=quad*4+r -> t][n=tcol -> d]
      const int tt = t0 + quad * 4 + r;
      float gacc = C[r];
      if (tt >= 32) gacc += pr[r];
      const float g = gacc * invLr[r];
      gb[(size_t)tt * D_ + d] = f2bf(g);
      const float e = x[(size_t)tt * D_ + d] * inrr[r] - g;
      sgl[r] += g * g;
      sdl[r] += e * e;
    }
  }
  #pragma unroll
  for (int r = 0; r < 4; ++r) {
    float sg2 = sgl[r], sd = sdl[r];
    sg2 += __shfl_xor(sg2, 1, 64); sg2 += __shfl_xor(sg2, 2, 64);
    sg2 += __shfl_xor(sg2, 4, 64); sg2 += __shfl_xor(sg2, 8, 64);
    sd += __shfl_xor(sd, 1, 64); sd += __shfl_xor(sd, 2, 64);
    sd += __shfl_xor(sd, 4, 64); sd += __shfl_xor(sd, 8, 64);
    if (tcol == 0) {
      atomicAdd(&gn2[t0 + quad * 4 + r], sg2);
      atomicAdd(&dist2[t0 + quad * 4 + r], sd);
    }
  }
}

// ---------- GEMM3: cross = g h^T, 64x128 causal tiles (1056 blocks); row-max ----------
// v10 config (best measured): 4 waves x (64 rows x 32 cols), per ks 6
// ds_read_b128 feed 8 MFMA; 24.3 KB LDS -> 6 blocks/CU.
__global__ __launch_bounds__(256, 5) void k_gemm3(const unsigned short* __restrict__ gb,
    const unsigned short* __restrict__ hb, const float* __restrict__ gn2,
    unsigned int* __restrict__ dmaxu) {
  // Bijective XCD swizzle: 1056 = 8*132.
  const int bswz = ((int)blockIdx.x & 7) * 132 + ((int)blockIdx.x >> 3);
  int ti, sj;
  tri2_decode(bswz, ti, sj);
  const int t0 = ti * 64, s0 = sj * 128;
  __shared__ unsigned short As[64 * 64];    // 8 KB  (t rows)
  __shared__ unsigned short Bs[128 * 64];   // 16 KB (s rows)
  __shared__ unsigned int dmx[64];          // per-block row-max merge
  const int tid = (int)threadIdx.x;
  const int lane = tid & 63, wv = tid >> 6;
  const int tcol = lane & 15, quad = lane >> 4;
  if (tid < 64) dmx[tid] = 0u;
  f32x4 acc[4][2] = {};

  for (int kc = 0; kc < 14; ++kc) {
    __syncthreads();   // prev chunk's reads done before overwrite (also fences dmx init)
    stage32(gb + (size_t)t0 * D_ + kc * 64, D_, As, tid);
    stage32(hb + (size_t)s0 * D_ + kc * 64, D_, Bs, tid);
    stage32(hb + (size_t)(s0 + 64) * D_ + kc * 64, D_, Bs + 64 * 64, tid);
    __syncthreads();   // staged data visible
    #pragma unroll
    for (int ks = 0; ks < 2; ++ks) {
      const int go = ((ks * 4 + quad) ^ (tcol & 7)) * 8;
      u16x8 bf[2], af[4];
      #pragma unroll
      for (int ni = 0; ni < 2; ++ni)
        bf[ni] = ld16(&Bs[(wv * 32 + ni * 16 + tcol) * 64 + go]);
      #pragma unroll
      for (int mi = 0; mi < 4; ++mi)
        af[mi] = ld16(&As[(mi * 16 + tcol) * 64 + go]);
      #pragma unroll
      for (int mi = 0; mi < 4; ++mi)
        #pragma unroll
        for (int ni = 0; ni < 2; ++ni)
          acc[mi][ni] = mfma16(af[mi], bf[ni], acc[mi][ni]);
    }
  }

  // epilogue: m2[t] = max over this wave's 32-col strip, merge in LDS, then global
  #pragma unroll
  for (int mi = 0; mi < 4; ++mi) {
    #pragma unroll
    for (int r = 0; r < 4; ++r) {
      const int t = t0 + mi * 16 + quad * 4 + r;
      const float gn = gn2[t];
      float m2 = 0.f;
      #pragma unroll
      for (int ni = 0; ni < 2; ++ni) {
        const int s = s0 + wv * 32 + ni * 16 + tcol;
        if (t >= s)
          m2 = fmaxf(m2, fmaxf(1.0f - 2.0f * acc[mi][ni][r] + gn, 1e-24f));
      }
      m2 = fmaxf(m2, __shfl_xor(m2, 1, 64));
      m2 = fmaxf(m2, __shfl_xor(m2, 2, 64));
      m2 = fmaxf(m2, __shfl_xor(m2, 4, 64));
      m2 = fmaxf(m2, __shfl_xor(m2, 8, 64));
      if (tcol == 0 && m2 > 0.f)
        atomicMax(&dmx[mi * 16 + quad * 4 + r], __float_as_uint(m2));
    }
  }
  __syncthreads();
  if (tid < 64) {
    const unsigned int v = dmx[tid];
    if (v) atomicMax(&dmaxu[t0 + tid], v);
  }
}

__global__ __launch_bounds__(256) void k_final(const float* __restrict__ m_t,
    const float* __restrict__ c_t, const float* __restrict__ d_t,
    const float* __restrict__ mu, const float* __restrict__ dist2,
    const unsigned int* __restrict__ dmaxu, float* __restrict__ out) {
  const int t = (int)blockIdx.x * 256 + (int)threadIdx.x;
  if (t >= T_) return;
  float ratio;
  if (t == 0) {
    ratio = 0.f;  // ref: dist~1e-12, dist_max<1e-6 -> 1.0 => ratio ~0
  } else {
    float dmax = sqrtf(__uint_as_float(dmaxu[t]));
    if (dmax < 1e-6f) dmax = 1.0f;
    ratio = sqrtf(fmaxf(dist2[t], 1e-24f)) / (dmax + 1e-8f);
  }
  const float stab = 1.0f - 0.3f * c_t[t] + 0.2f * d_t[t];
  const float xi = 1.0f - mu[0] * m_t[t];
  out[t] = fminf(fmaxf(ratio * stab * xi, 0.f), 1.f);
}

extern "C" void kernel_launch(void* const* d_in, const int* in_sizes, int n_in,
                              void* d_out, int out_size, void* d_ws, size_t ws_size,
                              hipStream_t stream) {
  const float* x   = (const float*)d_in[0];
  const float* m_t = (const float*)d_in[1];
  const float* c_t = (const float*)d_in[2];
  const float* d_t = (const float*)d_in[3];
  const float* mu  = (const float*)d_in[4];
  float* out = (float*)d_out;

  float* ws = (float*)d_ws;
  float* invnorm = ws;                                          // [T]
  unsigned int* dmaxu = (unsigned int*)(ws + (size_t)T_);       // [T]
  float* gn2     = ws + 2 * (size_t)T_;                         // [T]
  float* dist2   = ws + 3 * (size_t)T_;                         // [T]
  float* invLb   = ws + 4 * (size_t)T_;                         // [T]
  float* Sseg    = ws + 5 * (size_t)T_;                         // [256*D]
  float* Eseg    = Sseg + 256 * (size_t)D_;                     // [256*D]
  float* Pold    = Eseg + 256 * (size_t)D_;                     // (unused region)
  unsigned short* hb    = (unsigned short*)(Pold + (size_t)T_ * D_);  // [T*D]
  unsigned short* hbTp  = hb + (size_t)T_ * D_;                    // [D*(T+64)]
  unsigned short* gb    = hbTp + (size_t)D_ * TP;                  // [T*D]
  unsigned short* wband = gb + (size_t)T_ * D_;                    // [T*64]

  float* zero3 = ws + (size_t)T_;   // dmaxu+gn2+dist2, zeroed inside k_prep2

  k_prep2<<<T_ / 16, 256, 0, stream>>>(x, invnorm, hb, hbTp, Sseg, zero3);
  k_bandw<<<T_ / 16, 256, 0, stream>>>(hb, Sseg, Eseg, wband, invLb);
  k_bandg<<<dim3(T_ / 16, 8), 256, 0, stream>>>(hbTp, wband, invLb, Eseg, x, invnorm,
                                                gb, gn2, dist2);
  k_gemm3<<<1056, 256, 0, stream>>>(gb, hb, gn2, dmaxu);
  k_final<<<(T_ + 255) / 256, 256, 0, stream>>>(m_t, c_t, d_t, mu, dist2, dmaxu, out);
}